// Round 9
// baseline (322.694 us; speedup 1.0000x reference)
//
#include <hip/hip_runtime.h>
#include <cstdint>
#include <cstddef>

// Problem constants
constexpr int DD = 1024;        // D
constexpr int TT = 4096;        // T
constexpr int BB = 4;           // B
constexpr int MM = BB * TT;     // 16384 rows

typedef __bf16 bf16x8 __attribute__((ext_vector_type(8)));
typedef float  f32x4  __attribute__((ext_vector_type(4)));
typedef float  f32x16 __attribute__((ext_vector_type(16)));

__device__ __forceinline__ unsigned short f2bf(float f) {
  union { float f; uint32_t u; } c; c.f = f;
  uint32_t r = (c.u + 0x7FFFu + ((c.u >> 16) & 1u)) >> 16;
  return (unsigned short)r;
}

__device__ __forceinline__ float fast_rcp(float x) {
  return __builtin_amdgcn_rcpf(x);
}

// async global->LDS 16B per lane; lds_dst must be wave-uniform (HW adds lane*16)
__device__ __forceinline__ void async_ld16(const unsigned short* g, unsigned short* lds_dst) {
  __builtin_amdgcn_global_load_lds(
      (const __attribute__((address_space(1))) void*)g,
      (__attribute__((address_space(3))) void*)lds_dst,
      16, 0, 0);
}

// ---------------------------------------------------------------------------
// Merged prep (unchanged from R0).
__global__ void prep_all(const float* __restrict__ Wk, const float* __restrict__ Wv,
                         const float* __restrict__ Wr, const float* __restrict__ Wo,
                         const float* __restrict__ tmk, const float* __restrict__ tmv,
                         const float* __restrict__ tmr,
                         const float* __restrict__ last_x,
                         const float4* __restrict__ x,
                         unsigned short* __restrict__ wz,   // [3][1024][1024] bf16
                         unsigned short* __restrict__ wo,   // [1024][1024] bf16
                         float* __restrict__ bias,          // [3][1024]
                         ushort4* __restrict__ xb,          // [16384][1024] bf16
                         float4* __restrict__ out_xlast) {
  if (blockIdx.x < 1024) {
    int w = (blockIdx.x * 256 + threadIdx.x) >> 6;   // 0..4095
    int lane = threadIdx.x & 63;
    int z = w >> 10;           // 0..3
    int e = w & (DD - 1);
    const float* W  = (z == 0) ? Wk  : (z == 1) ? Wv  : (z == 2) ? Wr : Wo;
    const float* tm = (z == 0) ? tmk : (z == 1) ? tmv : tmr;
    unsigned short* dst = (z < 3) ? (wz + (size_t)z * DD * DD + (size_t)e * DD)
                                  : (wo + (size_t)e * DD);
    float s = 0.f;
#pragma unroll
    for (int j = 0; j < 4; ++j) {
      int d = j * 256 + lane * 4;
      float4 wv4 = *(const float4*)(W + (size_t)e * DD + d);
      if (z < 3) {
        float4 t4 = *(const float4*)(tm + d);
        float4 l4 = *(const float4*)(last_x + d);
        s += l4.x * (1.f - t4.x) * wv4.x + l4.y * (1.f - t4.y) * wv4.y +
             l4.z * (1.f - t4.z) * wv4.z + l4.w * (1.f - t4.w) * wv4.w;
        wv4.x *= t4.x; wv4.y *= t4.y; wv4.z *= t4.z; wv4.w *= t4.w;
      }
      ushort4 o;
      o.x = f2bf(wv4.x); o.y = f2bf(wv4.y); o.z = f2bf(wv4.z); o.w = f2bf(wv4.w);
      *(ushort4*)(dst + d) = o;
    }
    if (z < 3) {
      for (int off = 32; off; off >>= 1) s += __shfl_down(s, off, 64);
      if (lane == 0) bias[z * DD + e] = s;
    }
  } else {
    int i = (blockIdx.x - 1024) * 256 + threadIdx.x;  // < MM*DD/4
    float4 v = x[i];
    ushort4 o;
    o.x = f2bf(v.x); o.y = f2bf(v.y); o.z = f2bf(v.z); o.w = f2bf(v.w);
    xb[i] = o;
    int m = i >> 8;                                    // 256 float4 per row
    if ((m & (TT - 1)) == (TT - 1)) {
      int b = m >> 12;
      out_xlast[b * 256 + (i & 255)] = v;
    }
  }
}

// ---------------------------------------------------------------------------
// Variant A: byte-exact R0 structure (2-barrier two-panel BK=64, linear LDS,
// 16x16x32 MFMA), rows [0, 8192). CONTROL for the shape A/B.
__global__ __launch_bounds__(256, 2) void gemm_kvr_a(
    const unsigned short* __restrict__ A, const unsigned short* __restrict__ Wz,
    const float* __restrict__ bias,
    const float* __restrict__ time_first, const float* __restrict__ time_decay,
    const float* __restrict__ last_num, const float* __restrict__ last_den,
    unsigned short* __restrict__ rwkv,
    float* __restrict__ out_num, float* __restrict__ out_den) {
  __shared__ unsigned short lA[2][128 * 32];
  __shared__ unsigned short lB[2][3][64 * 32];
  const int tid  = threadIdx.x;
  const int lane = tid & 63;
  const int wave = tid >> 6;

  const int id  = blockIdx.y * gridDim.x + blockIdx.x;   // 0..1023
  const int xcd = id & 7;
  const int s   = id >> 3;                               // 0..127
  const int m0 = (xcd * 8 + (s >> 4)) * 128;             // stripes 0..63
  const int n0 = (s & 15) * 64;

  const int wm = (wave >> 1) * 64;
  const int wn = (wave & 1) * 32;

  f32x4 acc[3][4][2] = {};

  const int fr_row = lane & 15;
  const int fr_kb  = (lane >> 4) * 16;
  const int srow = tid >> 2;
  const int scol = (tid & 3) * 8;

  for (int k0 = 0; k0 < DD; k0 += 64) {
    __syncthreads();
#pragma unroll
    for (int h = 0; h < 2; ++h) {
      int kk = k0 + h * 32;
#pragma unroll
      for (int it = 0; it < 2; ++it) {
        int cc  = it * 256 + tid;
        int row = cc >> 2;
        async_ld16(A + (size_t)(m0 + row) * DD + (kk + scol),
                   lA[h] + (size_t)(it * 256 + wave * 64) * 8);
      }
#pragma unroll
      for (int z = 0; z < 3; ++z) {
        async_ld16(Wz + (size_t)z * DD * DD + (size_t)(n0 + srow) * DD + (kk + scol),
                   lB[h][z] + (size_t)(wave * 64) * 8);
      }
    }
    __syncthreads();

#pragma unroll
    for (int h = 0; h < 2; ++h) {
      bf16x8 af[4], bfr[3][2];
#pragma unroll
      for (int i = 0; i < 4; ++i)
        af[i] = *(const bf16x8*)((const char*)lA[h] + ((wm + i * 16 + fr_row) * 64 + fr_kb));
#pragma unroll
      for (int z = 0; z < 3; ++z)
#pragma unroll
        for (int j = 0; j < 2; ++j)
          bfr[z][j] = *(const bf16x8*)((const char*)lB[h][z] + ((wn + j * 16 + fr_row) * 64 + fr_kb));

#pragma unroll
      for (int mi = 0; mi < 4; ++mi)
#pragma unroll
        for (int z = 0; z < 3; ++z)
#pragma unroll
          for (int ni = 0; ni < 2; ++ni)
            acc[z][mi][ni] = __builtin_amdgcn_mfma_f32_16x16x32_bf16(
                af[mi], bfr[z][ni], acc[z][mi][ni], 0, 0, 0);
    }
  }

  // Epilogue (16x16 C/D layout: col=lane&15, row=(lane>>4)*4+reg).
  const int crow = (lane >> 4) * 4;
  const int ccol = lane & 15;
#pragma unroll
  for (int ni = 0; ni < 2; ++ni) {
    int gnz = n0 + wn + ni * 16 + ccol;
    float bk = bias[gnz], bv = bias[DD + gnz], br = bias[2 * DD + gnz];
    float tf = time_first[gnz];
    float ln = last_num[gnz], ld = last_den[gnz];
    float dec = __expf(-__expf(time_decay[gnz]));
#pragma unroll
    for (int mi = 0; mi < 4; ++mi) {
#pragma unroll
      for (int r = 0; r < 4; ++r) {
        int gm = m0 + wm + mi * 16 + crow + r;
        float kk = acc[0][mi][ni][r] + bk;
        float vv = acc[1][mi][ni][r] + bv;
        float rr = acc[2][mi][ni][r] + br;
        float efk = __expf(tf + kk);
        float wkv = (ln + efk * vv) * fast_rcp(ld + efk);
        float sr  = fast_rcp(1.0f + __expf(-rr));
        rwkv[(size_t)gm * DD + gnz] = f2bf(sr * wkv);
        if ((gm & (TT - 1)) == (TT - 1)) {
          int b = gm >> 12;
          float ek = __expf(kk);
          out_num[b * DD + gnz] = dec * ln + ek * vv;
          out_den[b * DD + gnz] = dec * ld + ek;
        }
      }
    }
  }
}

// ---------------------------------------------------------------------------
// Variant C: identical R0 structure/tiling/staging, but 32x32x16 MFMA,
// rows [8192, 16384). Per wave 64m x 32n x 3z = 2 m-subtiles x 1 n-tile of
// 32x32. Per K-half (32): 2 k-chunks of 16 -> 12 MFMA (vs 24 of 16x16),
// same 10 ds_read_b128. A/B frag: row=lane&31, k=(lane>>5)*8 elems.
// C/D: col=lane&31, row=(reg&3)+8*(reg>>2)+4*(lane>>5)  [guide m74/m101].
__global__ __launch_bounds__(256, 2) void gemm_kvr_c(
    const unsigned short* __restrict__ A, const unsigned short* __restrict__ Wz,
    const float* __restrict__ bias,
    const float* __restrict__ time_first, const float* __restrict__ time_decay,
    const float* __restrict__ last_num, const float* __restrict__ last_den,
    unsigned short* __restrict__ rwkv,
    float* __restrict__ out_num, float* __restrict__ out_den) {
  __shared__ unsigned short lA[2][128 * 32];
  __shared__ unsigned short lB[2][3][64 * 32];
  const int tid  = threadIdx.x;
  const int lane = tid & 63;
  const int wave = tid >> 6;

  const int id  = blockIdx.y * gridDim.x + blockIdx.x;   // 0..1023
  const int xcd = id & 7;
  const int s   = id >> 3;                               // 0..127
  const int m0 = 8192 + (xcd * 8 + (s >> 4)) * 128;      // stripes 64..127
  const int n0 = (s & 15) * 64;

  const int wm = (wave >> 1) * 64;
  const int wn = (wave & 1) * 32;

  f32x16 acc[3][2] = {};   // [z][m-subtile], 96 f32 total (same as variant A)

  const int frow = lane & 31;            // fragment row (A: m, B: n)
  const int fkb  = (lane >> 5) * 16;     // k byte offset within chunk (8 bf16)
  const int srow = tid >> 2;
  const int scol = (tid & 3) * 8;

  for (int k0 = 0; k0 < DD; k0 += 64) {
    __syncthreads();
#pragma unroll
    for (int h = 0; h < 2; ++h) {
      int kk = k0 + h * 32;
#pragma unroll
      for (int it = 0; it < 2; ++it) {
        int cc  = it * 256 + tid;
        int row = cc >> 2;
        async_ld16(A + (size_t)(m0 + row) * DD + (kk + scol),
                   lA[h] + (size_t)(it * 256 + wave * 64) * 8);
      }
#pragma unroll
      for (int z = 0; z < 3; ++z) {
        async_ld16(Wz + (size_t)z * DD * DD + (size_t)(n0 + srow) * DD + (kk + scol),
                   lB[h][z] + (size_t)(wave * 64) * 8);
      }
    }
    __syncthreads();

#pragma unroll
    for (int h = 0; h < 2; ++h) {
      // K-half = 32 -> 2 chunks of K=16. Same b128 count as variant A:
      // A: 2 mt x 2 c = 4; B: 3 z x 2 c = 6.
      bf16x8 af[2][2], bfr[3][2];
#pragma unroll
      for (int mt = 0; mt < 2; ++mt)
#pragma unroll
        for (int c = 0; c < 2; ++c)
          af[mt][c] = *(const bf16x8*)((const char*)lA[h] +
                        ((wm + mt * 32 + frow) * 64 + c * 32 + fkb));
#pragma unroll
      for (int z = 0; z < 3; ++z)
#pragma unroll
        for (int c = 0; c < 2; ++c)
          bfr[z][c] = *(const bf16x8*)((const char*)lB[h][z] +
                        ((wn + frow) * 64 + c * 32 + fkb));

#pragma unroll
      for (int mt = 0; mt < 2; ++mt)
#pragma unroll
        for (int z = 0; z < 3; ++z)
#pragma unroll
          for (int c = 0; c < 2; ++c)
            acc[z][mt] = __builtin_amdgcn_mfma_f32_32x32x16_bf16(
                af[mt][c], bfr[z][c], acc[z][mt], 0, 0, 0);
    }
  }

  // Epilogue (32x32 C/D layout).
  const int ccol = lane & 31;
  const int rbase = (lane >> 5) * 4;
  {
    int gnz = n0 + wn + ccol;
    float bk = bias[gnz], bv = bias[DD + gnz], br = bias[2 * DD + gnz];
    float tf = time_first[gnz];
    float ln = last_num[gnz], ld = last_den[gnz];
    float dec = __expf(-__expf(time_decay[gnz]));
#pragma unroll
    for (int mt = 0; mt < 2; ++mt) {
#pragma unroll
      for (int r = 0; r < 16; ++r) {
        int row = (r & 3) + 8 * (r >> 2) + rbase;
        int gm = m0 + wm + mt * 32 + row;
        float kk = acc[0][mt][r] + bk;
        float vv = acc[1][mt][r] + bv;
        float rr = acc[2][mt][r] + br;
        float efk = __expf(tf + kk);
        float wkv = (ln + efk * vv) * fast_rcp(ld + efk);
        float sr  = fast_rcp(1.0f + __expf(-rr));
        rwkv[(size_t)gm * DD + gnz] = f2bf(sr * wkv);
        if ((gm & (TT - 1)) == (TT - 1)) {
          int b = gm >> 12;
          float ek = __expf(kk);
          out_num[b * DD + gnz] = dec * ln + ek * vv;
          out_den[b * DD + gnz] = dec * ld + ek;
        }
      }
    }
  }
}

// ---------------------------------------------------------------------------
// GEMM2: byte-exact R0 gemm_bt128 (best-known config).
__global__ void gemm_bt128(const unsigned short* __restrict__ A,
                           const unsigned short* __restrict__ Bw,
                           float* __restrict__ Cf,
                           int M, int N, int K) {
  __shared__ unsigned short lA[2][128 * 32];
  __shared__ unsigned short lB[2][128 * 32];
  const int tid  = threadIdx.x;
  const int lane = tid & 63;
  const int wave = tid >> 6;

  const int nBlocks = N >> 7;
  const int mBlocks = M >> 7;
  const int id  = blockIdx.y * gridDim.x + blockIdx.x;
  const int xcd = id & 7;
  const int s   = id >> 3;
  const int mPer = mBlocks >> 3;
  const int m0 = (xcd * mPer + s / nBlocks) * 128;
  const int n0 = (s % nBlocks) * 128;

  const int wm = (wave >> 1) * 64;
  const int wn = (wave & 1) * 64;

  f32x4 acc[4][4] = {};
  const int fr_row = lane & 15;
  const int fr_kb  = (lane >> 4) * 16;
  const int scol = (tid & 3) * 8;

  for (int k0 = 0; k0 < K; k0 += 64) {
    __syncthreads();
#pragma unroll
    for (int h = 0; h < 2; ++h) {
      int kk = k0 + h * 32;
#pragma unroll
      for (int it = 0; it < 2; ++it) {
        int cc  = it * 256 + tid;
        int row = cc >> 2;
        async_ld16(A + (size_t)(m0 + row) * K + (kk + scol),
                   lA[h] + (size_t)(it * 256 + wave * 64) * 8);
      }
#pragma unroll
      for (int it = 0; it < 2; ++it) {
        int cc  = it * 256 + tid;
        int row = cc >> 2;
        async_ld16(Bw + (size_t)(n0 + row) * K + (kk + scol),
                   lB[h] + (size_t)(it * 256 + wave * 64) * 8);
      }
    }
    __syncthreads();

#pragma unroll
    for (int h = 0; h < 2; ++h) {
      bf16x8 af[4], bfr[4];
#pragma unroll
      for (int i = 0; i < 4; ++i) {
        af[i]  = *(const bf16x8*)((const char*)lA[h] + ((wm + i * 16 + fr_row) * 64 + fr_kb));
        bfr[i] = *(const bf16x8*)((const char*)lB[h] + ((wn + i * 16 + fr_row) * 64 + fr_kb));
      }
#pragma unroll
      for (int mi = 0; mi < 4; ++mi)
#pragma unroll
        for (int ni = 0; ni < 4; ++ni)
          acc[mi][ni] = __builtin_amdgcn_mfma_f32_16x16x32_bf16(af[mi], bfr[ni], acc[mi][ni], 0, 0, 0);
    }
  }

  const int crow = (lane >> 4) * 4;
  const int ccol = lane & 15;
#pragma unroll
  for (int mi = 0; mi < 4; ++mi) {
#pragma unroll
    for (int ni = 0; ni < 4; ++ni) {
      int gn = n0 + wn + ni * 16 + ccol;
#pragma unroll
      for (int r = 0; r < 4; ++r) {
        int gm = m0 + wm + mi * 16 + crow + r;
        Cf[(size_t)gm * N + gn] = acc[mi][ni][r];
      }
    }
  }
}

// ---------------------------------------------------------------------------
extern "C" void kernel_launch(void* const* d_in, const int* in_sizes, int n_in,
                              void* d_out, int out_size, void* d_ws, size_t ws_size,
                              hipStream_t stream) {
  const float* x          = (const float*)d_in[0];
  const float* last_x     = (const float*)d_in[1];
  const float* last_num   = (const float*)d_in[2];
  const float* last_den   = (const float*)d_in[3];
  const float* time_decay = (const float*)d_in[4];
  const float* time_first = (const float*)d_in[5];
  const float* tmk        = (const float*)d_in[6];
  const float* tmv        = (const float*)d_in[7];
  const float* tmr        = (const float*)d_in[8];
  const float* Wk         = (const float*)d_in[9];
  const float* Wv         = (const float*)d_in[10];
  const float* Wr         = (const float*)d_in[11];
  const float* Wo         = (const float*)d_in[12];

  float* out       = (float*)d_out;                  // [MM][DD]
  float* out_xlast = out + (size_t)MM * DD;          // [BB][DD]
  float* out_num   = out_xlast + BB * DD;            // [BB][DD]
  float* out_den   = out_num + BB * DD;              // [BB][DD]

  char* ws = (char*)d_ws;
  unsigned short* xb   = (unsigned short*)ws;                 // 33,554,432 B
  unsigned short* wz   = (unsigned short*)(ws + 33554432);    //  6,291,456 B
  unsigned short* wo   = (unsigned short*)(ws + 39845888);    //  2,097,152 B
  float*          bias = (float*)(ws + 41943040);             //     12,288 B
  unsigned short* rwkv = (unsigned short*)(ws + 41955328);    // 33,554,432 B

  prep_all<<<1024 + MM * DD / 4 / 256, 256, 0, stream>>>(
      Wk, Wv, Wr, Wo, tmk, tmv, tmr, last_x, (const float4*)x,
      wz, wo, bias, (ushort4*)xb, (float4*)out_xlast);

  // Shape A/B: control (16x16x32) on rows [0, 8192)
  gemm_kvr_a<<<dim3(16, 64), 256, 0, stream>>>(
      xb, wz, bias, time_first, time_decay, last_num, last_den,
      rwkv, out_num, out_den);

  // Probe (32x32x16) on rows [8192, 16384)
  gemm_kvr_c<<<dim3(16, 64), 256, 0, stream>>>(
      xb, wz, bias, time_first, time_decay, last_num, last_den,
      rwkv, out_num, out_den);

  // out = rwkv @ wo^T : [16384, 1024]
  gemm_bt128<<<dim3(DD / 128, MM / 128), 256, 0, stream>>>(
      rwkv, wo, out, MM, DD, DD);
}